// Round 5
// baseline (471.130 us; speedup 1.0000x reference)
//
#include <hip/hip_runtime.h>
#include <hip/hip_bf16.h>

#define N_NODES 50000
#define N_EDGES 800000
#define D 128

// ---------------- CSR build (by dst) ----------------
// Harness passes integer inputs as int32 (adj_list -> const int*).

__global__ void count_kernel(const int* __restrict__ adj, int* __restrict__ deg) {
    int e = blockIdx.x * blockDim.x + threadIdx.x;
    if (e < N_EDGES) {
        int d = adj[N_EDGES + e];
        atomicAdd(&deg[d], 1);
    }
}

// Single-block exclusive scan of deg[0..N) -> rowptr, cursor. 1024 threads.
__global__ __launch_bounds__(1024) void scan_kernel(const int* __restrict__ deg,
                                                    int* __restrict__ rowptr,
                                                    int* __restrict__ cursor) {
    const int CH = (N_NODES + 1023) / 1024;   // 49
    int tid = threadIdx.x;
    int lo = tid * CH, hi = min(lo + CH, N_NODES);
    if (lo > N_NODES) lo = N_NODES;
    int sum = 0;
    for (int i = lo; i < hi; ++i) sum += deg[i];

    int lane = tid & 63, wv = tid >> 6;
    int v = sum;
#pragma unroll
    for (int off = 1; off < 64; off <<= 1) {
        int t = __shfl_up(v, off);
        if (lane >= off) v += t;
    }
    __shared__ int wsum[16];
    if (lane == 63) wsum[wv] = v;
    __syncthreads();
    if (wv == 0 && lane < 16) {
        int t = wsum[lane];
#pragma unroll
        for (int off = 1; off < 16; off <<= 1) {
            int u = __shfl_up(t, off);
            if (lane >= off) t += u;
        }
        wsum[lane] = t;
    }
    __syncthreads();
    int base = (wv > 0 ? wsum[wv - 1] : 0) + v - sum;   // exclusive prefix of this thread
    int run = base;
    for (int i = lo; i < hi; ++i) {
        rowptr[i] = run;
        cursor[i] = run;
        run += deg[i];
    }
    if (tid == 1023) rowptr[N_NODES] = N_EDGES;
}

__global__ void scatter_kernel(const int* __restrict__ adj, int* __restrict__ cursor,
                               int* __restrict__ ssrc, int* __restrict__ sdst) {
    int e = blockIdx.x * blockDim.x + threadIdx.x;
    if (e < N_EDGES) {
        int d = adj[N_EDGES + e];
        int p = atomicAdd(&cursor[d], 1);
        ssrc[p] = adj[e];
        sdst[p] = d;
    }
}

// ---------------- per-edge attention weight (CSR order) ----------------
// ew[p] = exp(leaky_relu(AS[src] + AD[dst])). AS/AD are 200 KB -> L2-resident.
// Max-subtraction skipped: scores are O(+-10), exp stays in fp32 range, and
// exp(e)/sum exp(e) is shift-invariant.

__global__ __launch_bounds__(256) void edgew_kernel(
        const int* __restrict__ ssrc, const int* __restrict__ sdst,
        const float* __restrict__ AS, const float* __restrict__ AD,
        float* __restrict__ ew) {
    int e = blockIdx.x * 256 + threadIdx.x;
    if (e < N_EDGES) {
        float v = AS[ssrc[e]] + AD[sdst[e]];
        v = (v > 0.f) ? v : 0.2f * v;   // leaky_relu 0.2
        ew[e] = __expf(v);
    }
}

// ---------------- GEMM: H = X @ W, fused AS = H@a_src, AD = H@a_dst ----------------
// 256 threads (4 waves), block tile 64 rows x 128 cols, BK=32 (4 K-steps).
// Both operands in LDS (NO scalar/SMEM loads in the inner loop: SMEM shares
// lgkmcnt with DS and returns out-of-order -> forces lgkmcnt(0) drains; that
// was round-3's 23% VALUBusy).
// xt stored TRANSPOSED [k][row] stride 68 -> staging writes 2 lanes/bank (free),
// wt natural [k][col] stride 132. Micro-tile 8 rows x 4 cols per thread:
// per k: 3 x ds_read_b128 + 32 FMA -> LDS demand 0.75 B/flop < 69 TB/s roof.

#define BK 32
#define XT_S 68    // floats (17 float4)
#define WT_S 132   // floats (33 float4)

__global__ __launch_bounds__(256, 4) void gemm_kernel(
        const float* __restrict__ X, const float* __restrict__ W,
        const float* __restrict__ a_src, const float* __restrict__ a_dst,
        float* __restrict__ H, float* __restrict__ AS, float* __restrict__ AD) {
    __shared__ float xt[BK * XT_S];   // 8.7 KB
    __shared__ float wt[BK * WT_S];   // 16.9 KB
    int tid = threadIdx.x;
    int rg = tid >> 5;                // 0..7, owns rows rg*8..rg*8+7
    int cg = tid & 31;                // owns cols cg*4..cg*4+3
    int row0 = blockIdx.x * 64;

    float4 acc[8];
#pragma unroll
    for (int j = 0; j < 8; ++j) acc[j] = make_float4(0.f, 0.f, 0.f, 0.f);

    for (int ks = 0; ks < 4; ++ks) {
        int k0 = ks * BK;
        // stage W rows k0..k0+31 (1024 float4)
        {
            const float4* Wv = (const float4*)(W + (size_t)k0 * D);
            float4* wt4 = (float4*)wt;
#pragma unroll
            for (int i = 0; i < 4; ++i) {
                int f = tid + 256 * i;
                int k = f >> 5, c4 = f & 31;
                wt4[k * 33 + c4] = Wv[k * 32 + c4];
            }
        }
        // stage X rows row0..row0+63, cols k0..k0+31, transposed (512 float4 loads)
#pragma unroll
        for (int i = 0; i < 2; ++i) {
            int f = tid + 256 * i;
            int r = f >> 3, fi = f & 7;
            int gr = row0 + r; gr = (gr < N_NODES) ? gr : (N_NODES - 1);
            float4 xv = *(const float4*)&X[(size_t)gr * D + k0 + fi * 4];
            xt[(fi * 4 + 0) * XT_S + r] = xv.x;
            xt[(fi * 4 + 1) * XT_S + r] = xv.y;
            xt[(fi * 4 + 2) * XT_S + r] = xv.z;
            xt[(fi * 4 + 3) * XT_S + r] = xv.w;
        }
        __syncthreads();
#pragma unroll
        for (int k = 0; k < BK; ++k) {
            float4 xa = *(const float4*)&xt[k * XT_S + rg * 8];
            float4 xb = *(const float4*)&xt[k * XT_S + rg * 8 + 4];
            float4 wv = *(const float4*)&wt[k * WT_S + cg * 4];
            float xr[8] = {xa.x, xa.y, xa.z, xa.w, xb.x, xb.y, xb.z, xb.w};
#pragma unroll
            for (int j = 0; j < 8; ++j) {
                acc[j].x = fmaf(xr[j], wv.x, acc[j].x);
                acc[j].y = fmaf(xr[j], wv.y, acc[j].y);
                acc[j].z = fmaf(xr[j], wv.z, acc[j].z);
                acc[j].w = fmaf(xr[j], wv.w, acc[j].w);
            }
        }
        __syncthreads();
    }

    // epilogue: H writes + fused AS/AD (reduce over the 32 col-groups = lane&31)
    float4 asv = *(const float4*)&a_src[cg * 4];
    float4 adv = *(const float4*)&a_dst[cg * 4];
#pragma unroll
    for (int j = 0; j < 8; ++j) {
        int r = row0 + rg * 8 + j;
        if (r < N_NODES) *(float4*)&H[(size_t)r * D + cg * 4] = acc[j];
        float pa = acc[j].x * asv.x + acc[j].y * asv.y + acc[j].z * asv.z + acc[j].w * asv.w;
        float pd = acc[j].x * adv.x + acc[j].y * adv.y + acc[j].z * adv.z + acc[j].w * adv.w;
#pragma unroll
        for (int off = 16; off > 0; off >>= 1) {
            pa += __shfl_xor(pa, off);
            pd += __shfl_xor(pd, off);
        }
        if (cg == 0 && r < N_NODES) { AS[r] = pa; AD[r] = pd; }
    }
}

// ---------------- Aggregation: 2 waves per dst node, chunk-8 pipelined ----------------
// out[dst] = (sum_e ew[e] * h[src_e]) / (sum_e ew[e] + 1e-16) + bias
// block 256 = 4 waves = 2 nodes; node's CSR range split between its 2 waves;
// chunk-8 keeps 8 row-gathers in flight; lane l holds cols {2l, 2l+1}.
// LAYER==1 additionally applies t = relu(0.1*x + 0.9*out).

template <int LAYER>
__global__ __launch_bounds__(256, 8) void agg_kernel(
        const float* __restrict__ H, const float* __restrict__ ew,
        const int* __restrict__ rowptr, const int* __restrict__ ssrc,
        const float* __restrict__ bias, const float* __restrict__ Xskip,
        float* __restrict__ OUT) {
    int pair = threadIdx.x >> 7;            // 0/1: which node in block
    int sub  = (threadIdx.x >> 6) & 1;      // 0/1: which wave of the pair
    int l    = threadIdx.x & 63;
    int node = blockIdx.x * 2 + pair;       // grid = N/2 exactly, never OOB

    __shared__ float cacc[2][128];
    __shared__ float cs[2];

    int e0 = rowptr[node], e1 = rowptr[node + 1];
    int emid = (e0 + e1) >> 1;
    int lo = sub ? emid : e0;
    int hi = sub ? e1 : emid;

    float2 acc = make_float2(0.f, 0.f);
    float s = 0.f;

    while (lo + 8 <= hi) {
        int sn[8]; float wg[8]; float2 hv[8];
#pragma unroll
        for (int i = 0; i < 8; ++i) { sn[i] = ssrc[lo + i]; wg[i] = ew[lo + i]; }
#pragma unroll
        for (int i = 0; i < 8; ++i) hv[i] = *(const float2*)&H[(size_t)sn[i] * D + 2 * l];
#pragma unroll
        for (int i = 0; i < 8; ++i) {
            s += wg[i];
            acc.x = fmaf(wg[i], hv[i].x, acc.x);
            acc.y = fmaf(wg[i], hv[i].y, acc.y);
        }
        lo += 8;
    }
    if (lo + 4 <= hi) {
        int sn[4]; float wg[4]; float2 hv[4];
#pragma unroll
        for (int i = 0; i < 4; ++i) { sn[i] = ssrc[lo + i]; wg[i] = ew[lo + i]; }
#pragma unroll
        for (int i = 0; i < 4; ++i) hv[i] = *(const float2*)&H[(size_t)sn[i] * D + 2 * l];
#pragma unroll
        for (int i = 0; i < 4; ++i) {
            s += wg[i];
            acc.x = fmaf(wg[i], hv[i].x, acc.x);
            acc.y = fmaf(wg[i], hv[i].y, acc.y);
        }
        lo += 4;
    }
    for (; lo < hi; ++lo) {
        int sn = ssrc[lo]; float wg = ew[lo];
        float2 hv = *(const float2*)&H[(size_t)sn * D + 2 * l];
        s += wg;
        acc.x = fmaf(wg, hv.x, acc.x);
        acc.y = fmaf(wg, hv.y, acc.y);
    }

    if (sub == 1) {
        cacc[pair][2 * l]     = acc.x;
        cacc[pair][2 * l + 1] = acc.y;
        if (l == 0) cs[pair] = s;
    }
    __syncthreads();
    if (sub == 0) {
        acc.x += cacc[pair][2 * l];
        acc.y += cacc[pair][2 * l + 1];
        s += cs[pair];
        float inv = 1.f / (s + 1e-16f);
        float2 bv = ((const float2*)bias)[l];
        float o0 = acc.x * inv + bv.x;
        float o1 = acc.y * inv + bv.y;
        if (LAYER == 1) {
            float2 xs = *(const float2*)&Xskip[(size_t)node * D + 2 * l];
            o0 = fmaxf(0.1f * xs.x + 0.9f * o0, 0.f);
            o1 = fmaxf(0.1f * xs.y + 0.9f * o1, 0.f);
        }
        *(float2*)&OUT[(size_t)node * D + 2 * l] = make_float2(o0, o1);
    }
}

// ---------------- launcher ----------------

extern "C" void kernel_launch(void* const* d_in, const int* in_sizes, int n_in,
                              void* d_out, int out_size, void* d_ws, size_t ws_size,
                              hipStream_t stream) {
    const float* x   = (const float*)d_in[0];
    const int*   adj = (const int*)d_in[1];   // int32 per harness contract
    // d_in[2] = edge_attr, ignored (edge_dim=None in reference)
    const float* W1  = (const float*)d_in[3];
    const float* as1 = (const float*)d_in[4];
    const float* ad1 = (const float*)d_in[5];
    const float* b1  = (const float*)d_in[6];
    const float* W2  = (const float*)d_in[7];
    const float* as2 = (const float*)d_in[8];
    const float* ad2 = (const float*)d_in[9];
    const float* b2  = (const float*)d_in[10];
    float* out = (float*)d_out;

    char* ws = (char*)d_ws;
    size_t off = 0;
    auto alloc = [&](size_t bytes) -> void* {
        void* p = ws + off;
        off = (off + bytes + 255) & ~(size_t)255;
        return p;
    };
    float* H      = (float*)alloc((size_t)N_NODES * D * 4);   // 25.6 MB
    float* AS     = (float*)alloc((size_t)N_NODES * 4);
    float* AD     = (float*)alloc((size_t)N_NODES * 4);
    int*   deg    = (int*)alloc((size_t)N_NODES * 4);
    int*   rowptr = (int*)alloc((size_t)(N_NODES + 1) * 4);
    int*   cursor = (int*)alloc((size_t)N_NODES * 4);
    int*   ssrc   = (int*)alloc((size_t)N_EDGES * 4);         // 3.2 MB
    int*   sdst   = (int*)alloc((size_t)N_EDGES * 4);         // 3.2 MB
    float* ew     = (float*)alloc((size_t)N_EDGES * 4);       // 3.2 MB
    float* T      = out;   // layer-1 output lives in d_out; dead before final write

    const int EB = (N_EDGES + 255) / 256;

    hipMemsetAsync(deg, 0, (size_t)N_NODES * 4, stream);
    count_kernel<<<EB, 256, 0, stream>>>(adj, deg);
    scan_kernel<<<1, 1024, 0, stream>>>(deg, rowptr, cursor);
    scatter_kernel<<<EB, 256, 0, stream>>>(adj, cursor, ssrc, sdst);

    const int GB = (N_NODES + 63) / 64;     // 782
    const int AB = N_NODES / 2;             // 25000

    // layer 1
    gemm_kernel<<<GB, 256, 0, stream>>>(x, W1, as1, ad1, H, AS, AD);
    edgew_kernel<<<EB, 256, 0, stream>>>(ssrc, sdst, AS, AD, ew);
    agg_kernel<1><<<AB, 256, 0, stream>>>(H, ew, rowptr, ssrc, b1, x, T);
    // layer 2
    gemm_kernel<<<GB, 256, 0, stream>>>(T, W2, as2, ad2, H, AS, AD);
    edgew_kernel<<<EB, 256, 0, stream>>>(ssrc, sdst, AS, AD, ew);
    agg_kernel<2><<<AB, 256, 0, stream>>>(H, ew, rowptr, ssrc, b2, nullptr, out);
}

// Round 7
// 379.438 us; speedup vs baseline: 1.2417x; 1.2417x over previous
//
#include <hip/hip_runtime.h>
#include <hip/hip_bf16.h>

#define N_NODES 50000
#define N_EDGES 800000
#define D 128

// ---------------- CSR build (by dst) ----------------
// Harness passes integer inputs as int32 (adj_list -> const int*).

__global__ void count_kernel(const int* __restrict__ adj, int* __restrict__ deg) {
    int e = blockIdx.x * blockDim.x + threadIdx.x;
    if (e < N_EDGES) {
        int d = adj[N_EDGES + e];
        atomicAdd(&deg[d], 1);
    }
}

// 3-kernel parallel exclusive scan (196 blocks + 1 block + 196 blocks).
// NOTE: round-5 lesson — a single-block scan over 50K ints is 108 µs of pure
// latency (0.14% occupancy); the multi-block version is ~6 µs total.

__global__ void scan1_kernel(const int* __restrict__ deg, int* __restrict__ rowptr,
                             int* __restrict__ parts) {
    __shared__ int sm[256];
    int i = blockIdx.x * 256 + threadIdx.x;
    int v = (i < N_NODES) ? deg[i] : 0;
    sm[threadIdx.x] = v;
    __syncthreads();
    for (int off = 1; off < 256; off <<= 1) {
        int t = (threadIdx.x >= off) ? sm[threadIdx.x - off] : 0;
        __syncthreads();
        sm[threadIdx.x] += t;
        __syncthreads();
    }
    if (i < N_NODES) rowptr[i] = sm[threadIdx.x] - v;   // exclusive within block
    if (threadIdx.x == 255) parts[blockIdx.x] = sm[255];
}

__global__ void scan2_kernel(int* parts, int nb) {
    __shared__ int sm[256];
    int v = (threadIdx.x < nb) ? parts[threadIdx.x] : 0;
    sm[threadIdx.x] = v;
    __syncthreads();
    for (int off = 1; off < 256; off <<= 1) {
        int t = (threadIdx.x >= off) ? sm[threadIdx.x - off] : 0;
        __syncthreads();
        sm[threadIdx.x] += t;
        __syncthreads();
    }
    if (threadIdx.x < nb) parts[threadIdx.x] = sm[threadIdx.x] - v;  // exclusive
}

__global__ void scan3_kernel(int* __restrict__ rowptr, const int* __restrict__ parts,
                             int* __restrict__ cursor) {
    int i = blockIdx.x * 256 + threadIdx.x;
    if (i < N_NODES) {
        int v = rowptr[i] + parts[i >> 8];
        rowptr[i] = v;
        cursor[i] = v;
    }
    if (i == 0) rowptr[N_NODES] = N_EDGES;
}

__global__ void scatter_kernel(const int* __restrict__ adj, int* __restrict__ cursor,
                               int* __restrict__ ssrc, int* __restrict__ sdst) {
    int e = blockIdx.x * blockDim.x + threadIdx.x;
    if (e < N_EDGES) {
        int d = adj[N_EDGES + e];
        int p = atomicAdd(&cursor[d], 1);
        ssrc[p] = adj[e];
        sdst[p] = d;
    }
}

// ---------------- per-edge attention weight (CSR order) ----------------
// ew[p] = exp(leaky_relu(AS[src] + AD[dst])). AS/AD are 200 KB -> L2-resident.
// Max-subtraction skipped: scores are O(+-10), exp stays in fp32 range, and
// exp(e)/sum exp(e) is shift-invariant.

__global__ __launch_bounds__(256) void edgew_kernel(
        const int* __restrict__ ssrc, const int* __restrict__ sdst,
        const float* __restrict__ AS, const float* __restrict__ AD,
        float* __restrict__ ew) {
    int e = blockIdx.x * 256 + threadIdx.x;
    if (e < N_EDGES) {
        float v = AS[ssrc[e]] + AD[sdst[e]];
        v = (v > 0.f) ? v : 0.2f * v;   // leaky_relu 0.2
        ew[e] = __expf(v);
    }
}

// ---------------- GEMM: H = X @ W, fused AS = H@a_src, AD = H@a_dst ----------------
// 256 threads (4 waves), block tile 64 rows x 128 cols, BK=32 (4 K-steps).
// Both operands in LDS (NO scalar/SMEM loads in the inner loop: SMEM shares
// lgkmcnt with DS and returns out-of-order -> forces lgkmcnt(0) drains).
// xt stored TRANSPOSED [k][row] stride 68, wt natural [k][col] stride 132.
// Micro-tile 8 rows x 4 cols per thread: per k: 3 x ds_read_b128 + 32 FMA.

#define BK 32
#define XT_S 68    // floats (17 float4)
#define WT_S 132   // floats (33 float4)

__global__ __launch_bounds__(256, 4) void gemm_kernel(
        const float* __restrict__ X, const float* __restrict__ W,
        const float* __restrict__ a_src, const float* __restrict__ a_dst,
        float* __restrict__ H, float* __restrict__ AS, float* __restrict__ AD) {
    __shared__ float xt[BK * XT_S];   // 8.7 KB
    __shared__ float wt[BK * WT_S];   // 16.9 KB
    int tid = threadIdx.x;
    int rg = tid >> 5;                // 0..7, owns rows rg*8..rg*8+7
    int cg = tid & 31;                // owns cols cg*4..cg*4+3
    int row0 = blockIdx.x * 64;

    float4 acc[8];
#pragma unroll
    for (int j = 0; j < 8; ++j) acc[j] = make_float4(0.f, 0.f, 0.f, 0.f);

    for (int ks = 0; ks < 4; ++ks) {
        int k0 = ks * BK;
        // stage W rows k0..k0+31 (1024 float4)
        {
            const float4* Wv = (const float4*)(W + (size_t)k0 * D);
            float4* wt4 = (float4*)wt;
#pragma unroll
            for (int i = 0; i < 4; ++i) {
                int f = tid + 256 * i;
                int k = f >> 5, c4 = f & 31;
                wt4[k * 33 + c4] = Wv[k * 32 + c4];
            }
        }
        // stage X rows row0..row0+63, cols k0..k0+31, transposed
#pragma unroll
        for (int i = 0; i < 2; ++i) {
            int f = tid + 256 * i;
            int r = f >> 3, fi = f & 7;
            int gr = row0 + r; gr = (gr < N_NODES) ? gr : (N_NODES - 1);
            float4 xv = *(const float4*)&X[(size_t)gr * D + k0 + fi * 4];
            xt[(fi * 4 + 0) * XT_S + r] = xv.x;
            xt[(fi * 4 + 1) * XT_S + r] = xv.y;
            xt[(fi * 4 + 2) * XT_S + r] = xv.z;
            xt[(fi * 4 + 3) * XT_S + r] = xv.w;
        }
        __syncthreads();
#pragma unroll
        for (int k = 0; k < BK; ++k) {
            float4 xa = *(const float4*)&xt[k * XT_S + rg * 8];
            float4 xb = *(const float4*)&xt[k * XT_S + rg * 8 + 4];
            float4 wv = *(const float4*)&wt[k * WT_S + cg * 4];
            float xr[8] = {xa.x, xa.y, xa.z, xa.w, xb.x, xb.y, xb.z, xb.w};
#pragma unroll
            for (int j = 0; j < 8; ++j) {
                acc[j].x = fmaf(xr[j], wv.x, acc[j].x);
                acc[j].y = fmaf(xr[j], wv.y, acc[j].y);
                acc[j].z = fmaf(xr[j], wv.z, acc[j].z);
                acc[j].w = fmaf(xr[j], wv.w, acc[j].w);
            }
        }
        __syncthreads();
    }

    // epilogue: H writes + fused AS/AD (reduce over the 32 col-groups = lane&31)
    float4 asv = *(const float4*)&a_src[cg * 4];
    float4 adv = *(const float4*)&a_dst[cg * 4];
#pragma unroll
    for (int j = 0; j < 8; ++j) {
        int r = row0 + rg * 8 + j;
        if (r < N_NODES) *(float4*)&H[(size_t)r * D + cg * 4] = acc[j];
        float pa = acc[j].x * asv.x + acc[j].y * asv.y + acc[j].z * asv.z + acc[j].w * asv.w;
        float pd = acc[j].x * adv.x + acc[j].y * adv.y + acc[j].z * adv.z + acc[j].w * adv.w;
#pragma unroll
        for (int off = 16; off > 0; off >>= 1) {
            pa += __shfl_xor(pa, off);
            pd += __shfl_xor(pd, off);
        }
        if (cg == 0 && r < N_NODES) { AS[r] = pa; AD[r] = pd; }
    }
}

// ---------------- Aggregation: 2 waves per dst node, chunk-8 pipelined ----------------
// out[dst] = (sum_e ew[e] * h[src_e]) / (sum_e ew[e] + 1e-16) + bias
// block 256 = 4 waves = 2 nodes; node's CSR range split between its 2 waves;
// chunk-8 keeps 8 row-gathers in flight; lane l holds cols {2l, 2l+1}.
// LAYER==1 additionally applies t = relu(0.1*x + 0.9*out).

template <int LAYER>
__global__ __launch_bounds__(256, 8) void agg_kernel(
        const float* __restrict__ H, const float* __restrict__ ew,
        const int* __restrict__ rowptr, const int* __restrict__ ssrc,
        const float* __restrict__ bias, const float* __restrict__ Xskip,
        float* __restrict__ OUT) {
    int pair = threadIdx.x >> 7;            // 0/1: which node in block
    int sub  = (threadIdx.x >> 6) & 1;      // 0/1: which wave of the pair
    int l    = threadIdx.x & 63;
    int node = blockIdx.x * 2 + pair;       // grid = N/2 exactly, never OOB

    __shared__ float cacc[2][128];
    __shared__ float cs[2];

    int e0 = rowptr[node], e1 = rowptr[node + 1];
    int emid = (e0 + e1) >> 1;
    int lo = sub ? emid : e0;
    int hi = sub ? e1 : emid;

    float2 acc = make_float2(0.f, 0.f);
    float s = 0.f;

    while (lo + 8 <= hi) {
        int sn[8]; float wg[8]; float2 hv[8];
#pragma unroll
        for (int i = 0; i < 8; ++i) { sn[i] = ssrc[lo + i]; wg[i] = ew[lo + i]; }
#pragma unroll
        for (int i = 0; i < 8; ++i) hv[i] = *(const float2*)&H[(size_t)sn[i] * D + 2 * l];
#pragma unroll
        for (int i = 0; i < 8; ++i) {
            s += wg[i];
            acc.x = fmaf(wg[i], hv[i].x, acc.x);
            acc.y = fmaf(wg[i], hv[i].y, acc.y);
        }
        lo += 8;
    }
    if (lo + 4 <= hi) {
        int sn[4]; float wg[4]; float2 hv[4];
#pragma unroll
        for (int i = 0; i < 4; ++i) { sn[i] = ssrc[lo + i]; wg[i] = ew[lo + i]; }
#pragma unroll
        for (int i = 0; i < 4; ++i) hv[i] = *(const float2*)&H[(size_t)sn[i] * D + 2 * l];
#pragma unroll
        for (int i = 0; i < 4; ++i) {
            s += wg[i];
            acc.x = fmaf(wg[i], hv[i].x, acc.x);
            acc.y = fmaf(wg[i], hv[i].y, acc.y);
        }
        lo += 4;
    }
    for (; lo < hi; ++lo) {
        int sn = ssrc[lo]; float wg = ew[lo];
        float2 hv = *(const float2*)&H[(size_t)sn * D + 2 * l];
        s += wg;
        acc.x = fmaf(wg, hv.x, acc.x);
        acc.y = fmaf(wg, hv.y, acc.y);
    }

    if (sub == 1) {
        cacc[pair][2 * l]     = acc.x;
        cacc[pair][2 * l + 1] = acc.y;
        if (l == 0) cs[pair] = s;
    }
    __syncthreads();
    if (sub == 0) {
        acc.x += cacc[pair][2 * l];
        acc.y += cacc[pair][2 * l + 1];
        s += cs[pair];
        float inv = 1.f / (s + 1e-16f);
        float2 bv = ((const float2*)bias)[l];
        float o0 = acc.x * inv + bv.x;
        float o1 = acc.y * inv + bv.y;
        if (LAYER == 1) {
            float2 xs = *(const float2*)&Xskip[(size_t)node * D + 2 * l];
            o0 = fmaxf(0.1f * xs.x + 0.9f * o0, 0.f);
            o1 = fmaxf(0.1f * xs.y + 0.9f * o1, 0.f);
        }
        *(float2*)&OUT[(size_t)node * D + 2 * l] = make_float2(o0, o1);
    }
}

// ---------------- launcher ----------------

extern "C" void kernel_launch(void* const* d_in, const int* in_sizes, int n_in,
                              void* d_out, int out_size, void* d_ws, size_t ws_size,
                              hipStream_t stream) {
    const float* x   = (const float*)d_in[0];
    const int*   adj = (const int*)d_in[1];   // int32 per harness contract
    // d_in[2] = edge_attr, ignored (edge_dim=None in reference)
    const float* W1  = (const float*)d_in[3];
    const float* as1 = (const float*)d_in[4];
    const float* ad1 = (const float*)d_in[5];
    const float* b1  = (const float*)d_in[6];
    const float* W2  = (const float*)d_in[7];
    const float* as2 = (const float*)d_in[8];
    const float* ad2 = (const float*)d_in[9];
    const float* b2  = (const float*)d_in[10];
    float* out = (float*)d_out;

    char* ws = (char*)d_ws;
    size_t off = 0;
    auto alloc = [&](size_t bytes) -> void* {
        void* p = ws + off;
        off = (off + bytes + 255) & ~(size_t)255;
        return p;
    };
    float* H      = (float*)alloc((size_t)N_NODES * D * 4);   // 25.6 MB
    float* AS     = (float*)alloc((size_t)N_NODES * 4);
    float* AD     = (float*)alloc((size_t)N_NODES * 4);
    int*   deg    = (int*)alloc((size_t)N_NODES * 4);
    int*   rowptr = (int*)alloc((size_t)(N_NODES + 1) * 4);
    int*   cursor = (int*)alloc((size_t)N_NODES * 4);
    int*   ssrc   = (int*)alloc((size_t)N_EDGES * 4);         // 3.2 MB
    int*   sdst   = (int*)alloc((size_t)N_EDGES * 4);         // 3.2 MB
    float* ew     = (float*)alloc((size_t)N_EDGES * 4);       // 3.2 MB
    int*   parts  = (int*)alloc(256 * 4);
    float* T      = out;   // layer-1 output lives in d_out; dead before final write

    const int EB = (N_EDGES + 255) / 256;
    const int NB = (N_NODES + 255) / 256;   // 196

    hipMemsetAsync(deg, 0, (size_t)N_NODES * 4, stream);
    count_kernel<<<EB, 256, 0, stream>>>(adj, deg);
    scan1_kernel<<<NB, 256, 0, stream>>>(deg, rowptr, parts);
    scan2_kernel<<<1, 256, 0, stream>>>(parts, NB);
    scan3_kernel<<<NB, 256, 0, stream>>>(rowptr, parts, cursor);
    scatter_kernel<<<EB, 256, 0, stream>>>(adj, cursor, ssrc, sdst);

    const int GB = (N_NODES + 63) / 64;     // 782
    const int AB = N_NODES / 2;             // 25000

    // layer 1
    gemm_kernel<<<GB, 256, 0, stream>>>(x, W1, as1, ad1, H, AS, AD);
    edgew_kernel<<<EB, 256, 0, stream>>>(ssrc, sdst, AS, AD, ew);
    agg_kernel<1><<<AB, 256, 0, stream>>>(H, ew, rowptr, ssrc, b1, x, T);
    // layer 2
    gemm_kernel<<<GB, 256, 0, stream>>>(T, W2, as2, ad2, H, AS, AD);
    edgew_kernel<<<EB, 256, 0, stream>>>(ssrc, sdst, AS, AD, ew);
    agg_kernel<2><<<AB, 256, 0, stream>>>(H, ew, rowptr, ssrc, b2, nullptr, out);
}

// Round 10
// 377.275 us; speedup vs baseline: 1.2488x; 1.0057x over previous
//
#include <hip/hip_runtime.h>
#include <hip/hip_bf16.h>

#define N_NODES 50000
#define N_EDGES 800000
#define D 128

// ---------------- CSR build (by dst) ----------------
// Harness passes integer inputs as int32 (adj_list -> const int*).

__global__ void count_kernel(const int* __restrict__ adj, int* __restrict__ deg) {
    int e = blockIdx.x * blockDim.x + threadIdx.x;
    if (e < N_EDGES) {
        int d = adj[N_EDGES + e];
        atomicAdd(&deg[d], 1);
    }
}

// 3-kernel parallel exclusive scan (round-5 lesson: single-block scan = 108 µs
// of pure latency; this multi-block version is ~6 µs total).

__global__ void scan1_kernel(const int* __restrict__ deg, int* __restrict__ rowptr,
                             int* __restrict__ parts) {
    __shared__ int sm[256];
    int i = blockIdx.x * 256 + threadIdx.x;
    int v = (i < N_NODES) ? deg[i] : 0;
    sm[threadIdx.x] = v;
    __syncthreads();
    for (int off = 1; off < 256; off <<= 1) {
        int t = (threadIdx.x >= off) ? sm[threadIdx.x - off] : 0;
        __syncthreads();
        sm[threadIdx.x] += t;
        __syncthreads();
    }
    if (i < N_NODES) rowptr[i] = sm[threadIdx.x] - v;   // exclusive within block
    if (threadIdx.x == 255) parts[blockIdx.x] = sm[255];
}

__global__ void scan2_kernel(int* parts, int nb) {
    __shared__ int sm[256];
    int v = (threadIdx.x < nb) ? parts[threadIdx.x] : 0;
    sm[threadIdx.x] = v;
    __syncthreads();
    for (int off = 1; off < 256; off <<= 1) {
        int t = (threadIdx.x >= off) ? sm[threadIdx.x - off] : 0;
        __syncthreads();
        sm[threadIdx.x] += t;
        __syncthreads();
    }
    if (threadIdx.x < nb) parts[threadIdx.x] = sm[threadIdx.x] - v;  // exclusive
}

__global__ void scan3_kernel(int* __restrict__ rowptr, const int* __restrict__ parts,
                             int* __restrict__ cursor) {
    int i = blockIdx.x * 256 + threadIdx.x;
    if (i < N_NODES) {
        int v = rowptr[i] + parts[i >> 8];
        rowptr[i] = v;
        cursor[i] = v;
    }
    if (i == 0) rowptr[N_NODES] = N_EDGES;
}

__global__ void scatter_kernel(const int* __restrict__ adj, int* __restrict__ cursor,
                               int* __restrict__ ssrc) {
    int e = blockIdx.x * blockDim.x + threadIdx.x;
    if (e < N_EDGES) {
        int d = adj[N_EDGES + e];
        int p = atomicAdd(&cursor[d], 1);
        ssrc[p] = adj[e];
    }
}

// ---------------- GEMM: H = X @ W, fused AS = H@a_src, AD = H@a_dst ----------------
// 256 threads (4 waves), block tile 64 rows x 128 cols, BK=32 (4 K-steps).
// Both operands in LDS; register double-buffer: next K-tile's global loads are
// issued right after the first barrier so their latency overlaps the 32-step
// FMA block (previously they serialized after the barrier).
// xt stored TRANSPOSED [k][row] stride 68, wt natural [k][col] stride 132.

#define BK 32
#define XT_S 68    // floats
#define WT_S 132   // floats (33 float4)

__global__ __launch_bounds__(256, 4) void gemm_kernel(
        const float* __restrict__ X, const float* __restrict__ W,
        const float* __restrict__ a_src, const float* __restrict__ a_dst,
        float* __restrict__ H, float* __restrict__ AS, float* __restrict__ AD) {
    __shared__ float xt[BK * XT_S];   // 8.7 KB
    __shared__ float wt[BK * WT_S];   // 16.9 KB
    int tid = threadIdx.x;
    int rg = tid >> 5;                // 0..7, owns rows rg*8..rg*8+7
    int cg = tid & 31;                // owns cols cg*4..cg*4+3
    int row0 = blockIdx.x * 64;

    float4 acc[8];
#pragma unroll
    for (int j = 0; j < 8; ++j) acc[j] = make_float4(0.f, 0.f, 0.f, 0.f);

    float4 wreg[4], xreg[2];
    auto loadw = [&](int ks) {
        const float4* Wv = (const float4*)(W + (size_t)ks * BK * D);
#pragma unroll
        for (int i = 0; i < 4; ++i) {
            int f = tid + 256 * i;
            wreg[i] = Wv[(f >> 5) * 32 + (f & 31)];
        }
    };
    auto loadx = [&](int ks) {
#pragma unroll
        for (int i = 0; i < 2; ++i) {
            int f = tid + 256 * i;
            int r = f >> 3, fi = f & 7;
            int gr = row0 + r; gr = (gr < N_NODES) ? gr : (N_NODES - 1);
            xreg[i] = *(const float4*)&X[(size_t)gr * D + ks * BK + fi * 4];
        }
    };

    loadw(0); loadx(0);
    for (int ks = 0; ks < 4; ++ks) {
        // LDS write from registers
        {
            float4* wt4 = (float4*)wt;
#pragma unroll
            for (int i = 0; i < 4; ++i) {
                int f = tid + 256 * i;
                wt4[(f >> 5) * 33 + (f & 31)] = wreg[i];
            }
#pragma unroll
            for (int i = 0; i < 2; ++i) {
                int f = tid + 256 * i;
                int r = f >> 3, fi = f & 7;
                xt[(fi * 4 + 0) * XT_S + r] = xreg[i].x;
                xt[(fi * 4 + 1) * XT_S + r] = xreg[i].y;
                xt[(fi * 4 + 2) * XT_S + r] = xreg[i].z;
                xt[(fi * 4 + 3) * XT_S + r] = xreg[i].w;
            }
        }
        __syncthreads();
        if (ks < 3) { loadw(ks + 1); loadx(ks + 1); }   // overlap with compute
#pragma unroll
        for (int k = 0; k < BK; ++k) {
            float4 xa = *(const float4*)&xt[k * XT_S + rg * 8];
            float4 xb = *(const float4*)&xt[k * XT_S + rg * 8 + 4];
            float4 wv = *(const float4*)&wt[k * WT_S + cg * 4];
            float xr[8] = {xa.x, xa.y, xa.z, xa.w, xb.x, xb.y, xb.z, xb.w};
#pragma unroll
            for (int j = 0; j < 8; ++j) {
                acc[j].x = fmaf(xr[j], wv.x, acc[j].x);
                acc[j].y = fmaf(xr[j], wv.y, acc[j].y);
                acc[j].z = fmaf(xr[j], wv.z, acc[j].z);
                acc[j].w = fmaf(xr[j], wv.w, acc[j].w);
            }
        }
        __syncthreads();
    }

    // epilogue: H writes + fused AS/AD (reduce over the 32 col-groups = lane&31)
    float4 asv = *(const float4*)&a_src[cg * 4];
    float4 adv = *(const float4*)&a_dst[cg * 4];
#pragma unroll
    for (int j = 0; j < 8; ++j) {
        int r = row0 + rg * 8 + j;
        if (r < N_NODES) *(float4*)&H[(size_t)r * D + cg * 4] = acc[j];
        float pa = acc[j].x * asv.x + acc[j].y * asv.y + acc[j].z * asv.z + acc[j].w * asv.w;
        float pd = acc[j].x * adv.x + acc[j].y * adv.y + acc[j].z * adv.z + acc[j].w * adv.w;
#pragma unroll
        for (int off = 16; off > 0; off >>= 1) {
            pa += __shfl_xor(pa, off);
            pd += __shfl_xor(pd, off);
        }
        if (cg == 0 && r < N_NODES) { AS[r] = pa; AD[r] = pd; }
    }
}

// ---------------- Aggregation: 1 wave per dst node, chunk-16, fused weights ----------
// out[dst] = (sum_e w_e * h[src_e]) / (sum_e w_e + 1e-16) + bias
//   w_e = exp(leaky_relu(AS[src_e] + AD[dst], 0.2))   (computed inline; the
//   separate edgew pass + ew array are gone). Max-subtraction skipped: scores
//   are O(+-10), exp stays in fp32 range, softmax is shift-invariant.
// chunk-16: 16 ssrc broadcast loads -> 16 AS 4B-gathers + 16 H row-gathers all
// in flight; masked final chunk (clamped index, w=0) -> NO serial tail edges.
// Clamped duplicate gathers hit the same row -> L1-served, negligible.
// LAYER==1 additionally applies t = relu(0.1*x + 0.9*out).

template <int LAYER>
__global__ __launch_bounds__(256, 4) void agg_kernel(
        const float* __restrict__ H, const float* __restrict__ AS,
        const float* __restrict__ AD,
        const int* __restrict__ rowptr, const int* __restrict__ ssrc,
        const float* __restrict__ bias, const float* __restrict__ Xskip,
        float* __restrict__ OUT) {
    int wave = threadIdx.x >> 6;
    int l    = threadIdx.x & 63;
    int node = blockIdx.x * 4 + wave;       // grid = N/4 exactly, never OOB

    int e0 = rowptr[node], e1 = rowptr[node + 1];
    float adn = AD[node];
    float2 acc = make_float2(0.f, 0.f);
    float s = 0.f;
    int lo = e0;

    while (lo + 16 <= e1) {
        int sn[16]; float asv[16]; float2 hv[16];
#pragma unroll
        for (int i = 0; i < 16; ++i) sn[i] = ssrc[lo + i];
#pragma unroll
        for (int i = 0; i < 16; ++i) asv[i] = AS[sn[i]];
#pragma unroll
        for (int i = 0; i < 16; ++i) hv[i] = *(const float2*)&H[(size_t)sn[i] * D + 2 * l];
#pragma unroll
        for (int i = 0; i < 16; ++i) {
            float v = asv[i] + adn;
            v = (v > 0.f) ? v : 0.2f * v;
            float w = __expf(v);
            s += w;
            acc.x = fmaf(w, hv[i].x, acc.x);
            acc.y = fmaf(w, hv[i].y, acc.y);
        }
        lo += 16;
    }
    if (lo < e1) {                            // masked final chunk, no serial tail
        int n = e1 - lo;
        int sn[16]; float asv[16]; float2 hv[16];
#pragma unroll
        for (int i = 0; i < 16; ++i) {
            int e = lo + ((i < n) ? i : (n - 1));
            sn[i] = ssrc[e];
        }
#pragma unroll
        for (int i = 0; i < 16; ++i) asv[i] = AS[sn[i]];
#pragma unroll
        for (int i = 0; i < 16; ++i) hv[i] = *(const float2*)&H[(size_t)sn[i] * D + 2 * l];
#pragma unroll
        for (int i = 0; i < 16; ++i) {
            float v = asv[i] + adn;
            v = (v > 0.f) ? v : 0.2f * v;
            float w = (i < n) ? __expf(v) : 0.f;
            s += w;
            acc.x = fmaf(w, hv[i].x, acc.x);
            acc.y = fmaf(w, hv[i].y, acc.y);
        }
    }

    float inv = 1.f / (s + 1e-16f);
    float2 bv = ((const float2*)bias)[l];
    float o0 = acc.x * inv + bv.x;
    float o1 = acc.y * inv + bv.y;
    if (LAYER == 1) {
        float2 xs = *(const float2*)&Xskip[(size_t)node * D + 2 * l];
        o0 = fmaxf(0.1f * xs.x + 0.9f * o0, 0.f);
        o1 = fmaxf(0.1f * xs.y + 0.9f * o1, 0.f);
    }
    *(float2*)&OUT[(size_t)node * D + 2 * l] = make_float2(o0, o1);
}

// ---------------- launcher ----------------

extern "C" void kernel_launch(void* const* d_in, const int* in_sizes, int n_in,
                              void* d_out, int out_size, void* d_ws, size_t ws_size,
                              hipStream_t stream) {
    const float* x   = (const float*)d_in[0];
    const int*   adj = (const int*)d_in[1];   // int32 per harness contract
    // d_in[2] = edge_attr, ignored (edge_dim=None in reference)
    const float* W1  = (const float*)d_in[3];
    const float* as1 = (const float*)d_in[4];
    const float* ad1 = (const float*)d_in[5];
    const float* b1  = (const float*)d_in[6];
    const float* W2  = (const float*)d_in[7];
    const float* as2 = (const float*)d_in[8];
    const float* ad2 = (const float*)d_in[9];
    const float* b2  = (const float*)d_in[10];
    float* out = (float*)d_out;

    char* ws = (char*)d_ws;
    size_t off = 0;
    auto alloc = [&](size_t bytes) -> void* {
        void* p = ws + off;
        off = (off + bytes + 255) & ~(size_t)255;
        return p;
    };
    float* H      = (float*)alloc((size_t)N_NODES * D * 4);   // 25.6 MB
    float* AS     = (float*)alloc((size_t)N_NODES * 4);
    float* AD     = (float*)alloc((size_t)N_NODES * 4);
    int*   deg    = (int*)alloc((size_t)N_NODES * 4);
    int*   rowptr = (int*)alloc((size_t)(N_NODES + 1) * 4);
    int*   cursor = (int*)alloc((size_t)N_NODES * 4);
    int*   ssrc   = (int*)alloc((size_t)N_EDGES * 4);         // 3.2 MB
    int*   parts  = (int*)alloc(256 * 4);
    float* T      = out;   // layer-1 output lives in d_out; dead before final write

    const int EB = (N_EDGES + 255) / 256;
    const int NB = (N_NODES + 255) / 256;   // 196

    hipMemsetAsync(deg, 0, (size_t)N_NODES * 4, stream);
    count_kernel<<<EB, 256, 0, stream>>>(adj, deg);
    scan1_kernel<<<NB, 256, 0, stream>>>(deg, rowptr, parts);
    scan2_kernel<<<1, 256, 0, stream>>>(parts, NB);
    scan3_kernel<<<NB, 256, 0, stream>>>(rowptr, parts, cursor);
    scatter_kernel<<<EB, 256, 0, stream>>>(adj, cursor, ssrc);

    const int GB = (N_NODES + 63) / 64;     // 782
    const int AB = (N_NODES + 3) / 4;       // 12500 (4 nodes/block, 1 wave each)

    // layer 1
    gemm_kernel<<<GB, 256, 0, stream>>>(x, W1, as1, ad1, H, AS, AD);
    agg_kernel<1><<<AB, 256, 0, stream>>>(H, AS, AD, rowptr, ssrc, b1, x, T);
    // layer 2
    gemm_kernel<<<GB, 256, 0, stream>>>(T, W2, as2, ad2, H, AS, AD);
    agg_kernel<2><<<AB, 256, 0, stream>>>(H, AS, AD, rowptr, ssrc, b2, nullptr, out);
}

// Round 11
// 328.112 us; speedup vs baseline: 1.4359x; 1.1498x over previous
//
#include <hip/hip_runtime.h>
#include <hip/hip_bf16.h>

#define N_NODES 50000
#define N_EDGES 800000
#define D 128

// ---------------- CSR build (by dst) ----------------
// Harness passes integer inputs as int32 (adj_list -> const int*).

__global__ void count_kernel(const int* __restrict__ adj, int* __restrict__ deg) {
    int e = blockIdx.x * blockDim.x + threadIdx.x;
    if (e < N_EDGES) {
        int d = adj[N_EDGES + e];
        atomicAdd(&deg[d], 1);
    }
}

// 3-kernel parallel exclusive scan (round-5 lesson: single-block scan = 108 µs
// of pure latency; this multi-block version is ~6 µs total).

__global__ void scan1_kernel(const int* __restrict__ deg, int* __restrict__ rowptr,
                             int* __restrict__ parts) {
    __shared__ int sm[256];
    int i = blockIdx.x * 256 + threadIdx.x;
    int v = (i < N_NODES) ? deg[i] : 0;
    sm[threadIdx.x] = v;
    __syncthreads();
    for (int off = 1; off < 256; off <<= 1) {
        int t = (threadIdx.x >= off) ? sm[threadIdx.x - off] : 0;
        __syncthreads();
        sm[threadIdx.x] += t;
        __syncthreads();
    }
    if (i < N_NODES) rowptr[i] = sm[threadIdx.x] - v;   // exclusive within block
    if (threadIdx.x == 255) parts[blockIdx.x] = sm[255];
}

__global__ void scan2_kernel(int* parts, int nb) {
    __shared__ int sm[256];
    int v = (threadIdx.x < nb) ? parts[threadIdx.x] : 0;
    sm[threadIdx.x] = v;
    __syncthreads();
    for (int off = 1; off < 256; off <<= 1) {
        int t = (threadIdx.x >= off) ? sm[threadIdx.x - off] : 0;
        __syncthreads();
        sm[threadIdx.x] += t;
        __syncthreads();
    }
    if (threadIdx.x < nb) parts[threadIdx.x] = sm[threadIdx.x] - v;  // exclusive
}

__global__ void scan3_kernel(int* __restrict__ rowptr, const int* __restrict__ parts,
                             int* __restrict__ cursor) {
    int i = blockIdx.x * 256 + threadIdx.x;
    if (i < N_NODES) {
        int v = rowptr[i] + parts[i >> 8];
        rowptr[i] = v;
        cursor[i] = v;
    }
    if (i == 0) rowptr[N_NODES] = N_EDGES;
}

__global__ void scatter_kernel(const int* __restrict__ adj, int* __restrict__ cursor,
                               int* __restrict__ ssrc) {
    int e = blockIdx.x * blockDim.x + threadIdx.x;
    if (e < N_EDGES) {
        int d = adj[N_EDGES + e];
        int p = atomicAdd(&cursor[d], 1);
        ssrc[p] = adj[e];
    }
}

// ---------------- GEMM: Hb(bf16) = X @ W, fused AS = H@a_src, AD = H@a_dst --------
// 256 threads (4 waves), block tile 64 rows x 128 cols, BK=32 (4 K-steps).
// Both operands in LDS; register double-buffer overlaps next K-tile's global
// loads with the FMA block. AS/AD computed from the fp32 accumulators (full
// precision); only the stored H is bf16 (halves agg's gather bytes — the agg
// fetch rate ~3.3 TB/s proved to be a HW ceiling for random row-gathers, so
// bytes, not scheduling, is the remaining lever).

#define BK 32
#define XT_S 68    // floats
#define WT_S 132   // floats (33 float4)

__global__ __launch_bounds__(256, 4) void gemm_kernel(
        const float* __restrict__ X, const float* __restrict__ W,
        const float* __restrict__ a_src, const float* __restrict__ a_dst,
        __hip_bfloat16* __restrict__ Hb, float* __restrict__ AS, float* __restrict__ AD) {
    __shared__ float xt[BK * XT_S];   // 8.7 KB
    __shared__ float wt[BK * WT_S];   // 16.9 KB
    int tid = threadIdx.x;
    int rg = tid >> 5;                // 0..7, owns rows rg*8..rg*8+7
    int cg = tid & 31;                // owns cols cg*4..cg*4+3
    int row0 = blockIdx.x * 64;

    float4 acc[8];
#pragma unroll
    for (int j = 0; j < 8; ++j) acc[j] = make_float4(0.f, 0.f, 0.f, 0.f);

    float4 wreg[4], xreg[2];
    auto loadw = [&](int ks) {
        const float4* Wv = (const float4*)(W + (size_t)ks * BK * D);
#pragma unroll
        for (int i = 0; i < 4; ++i) {
            int f = tid + 256 * i;
            wreg[i] = Wv[(f >> 5) * 32 + (f & 31)];
        }
    };
    auto loadx = [&](int ks) {
#pragma unroll
        for (int i = 0; i < 2; ++i) {
            int f = tid + 256 * i;
            int r = f >> 3, fi = f & 7;
            int gr = row0 + r; gr = (gr < N_NODES) ? gr : (N_NODES - 1);
            xreg[i] = *(const float4*)&X[(size_t)gr * D + ks * BK + fi * 4];
        }
    };

    loadw(0); loadx(0);
    for (int ks = 0; ks < 4; ++ks) {
        {
            float4* wt4 = (float4*)wt;
#pragma unroll
            for (int i = 0; i < 4; ++i) {
                int f = tid + 256 * i;
                wt4[(f >> 5) * 33 + (f & 31)] = wreg[i];
            }
#pragma unroll
            for (int i = 0; i < 2; ++i) {
                int f = tid + 256 * i;
                int r = f >> 3, fi = f & 7;
                xt[(fi * 4 + 0) * XT_S + r] = xreg[i].x;
                xt[(fi * 4 + 1) * XT_S + r] = xreg[i].y;
                xt[(fi * 4 + 2) * XT_S + r] = xreg[i].z;
                xt[(fi * 4 + 3) * XT_S + r] = xreg[i].w;
            }
        }
        __syncthreads();
        if (ks < 3) { loadw(ks + 1); loadx(ks + 1); }   // overlap with compute
#pragma unroll
        for (int k = 0; k < BK; ++k) {
            float4 xa = *(const float4*)&xt[k * XT_S + rg * 8];
            float4 xb = *(const float4*)&xt[k * XT_S + rg * 8 + 4];
            float4 wv = *(const float4*)&wt[k * WT_S + cg * 4];
            float xr[8] = {xa.x, xa.y, xa.z, xa.w, xb.x, xb.y, xb.z, xb.w};
#pragma unroll
            for (int j = 0; j < 8; ++j) {
                acc[j].x = fmaf(xr[j], wv.x, acc[j].x);
                acc[j].y = fmaf(xr[j], wv.y, acc[j].y);
                acc[j].z = fmaf(xr[j], wv.z, acc[j].z);
                acc[j].w = fmaf(xr[j], wv.w, acc[j].w);
            }
        }
        __syncthreads();
    }

    // epilogue: bf16 H writes + fused AS/AD (fp32 accs; reduce over 32 col-groups)
    float4 asv = *(const float4*)&a_src[cg * 4];
    float4 adv = *(const float4*)&a_dst[cg * 4];
#pragma unroll
    for (int j = 0; j < 8; ++j) {
        int r = row0 + rg * 8 + j;
        if (r < N_NODES) {
            __hip_bfloat16 hb[4] = {__float2bfloat16(acc[j].x), __float2bfloat16(acc[j].y),
                                    __float2bfloat16(acc[j].z), __float2bfloat16(acc[j].w)};
            *(ushort4*)&Hb[(size_t)r * D + cg * 4] = *(const ushort4*)hb;
        }
        float pa = acc[j].x * asv.x + acc[j].y * asv.y + acc[j].z * asv.z + acc[j].w * asv.w;
        float pd = acc[j].x * adv.x + acc[j].y * adv.y + acc[j].z * adv.z + acc[j].w * adv.w;
#pragma unroll
        for (int off = 16; off > 0; off >>= 1) {
            pa += __shfl_xor(pa, off);
            pd += __shfl_xor(pd, off);
        }
        if (cg == 0 && r < N_NODES) { AS[r] = pa; AD[r] = pd; }
    }
}

// ---------------- Aggregation: 1 wave per dst node, chunk-16, bf16 H gather --------
// out[dst] = (sum_e w_e * h[src_e]) / (sum_e w_e + 1e-16) + bias
//   w_e = exp(leaky_relu(AS[src_e] + AD[dst], 0.2)) computed inline (fp32).
// bf16 rows: 256 B/edge; lane l loads one uint = cols {2l, 2l+1}, unpacked by
// bit-shift (bf16 -> f32 is exact). Max-subtraction skipped: scores O(+-10),
// softmax shift-invariant. Masked final chunk -> no serial tail.
// LAYER==1 additionally applies t = relu(0.1*x + 0.9*out).

template <int LAYER>
__global__ __launch_bounds__(256, 4) void agg_kernel(
        const __hip_bfloat16* __restrict__ Hb, const float* __restrict__ AS,
        const float* __restrict__ AD,
        const int* __restrict__ rowptr, const int* __restrict__ ssrc,
        const float* __restrict__ bias, const float* __restrict__ Xskip,
        float* __restrict__ OUT) {
    int wave = threadIdx.x >> 6;
    int l    = threadIdx.x & 63;
    int node = blockIdx.x * 4 + wave;       // grid = N/4 exactly, never OOB

    int e0 = rowptr[node], e1 = rowptr[node + 1];
    float adn = AD[node];
    float2 acc = make_float2(0.f, 0.f);
    float s = 0.f;
    int lo = e0;

    while (lo + 16 <= e1) {
        int sn[16]; float asv[16]; unsigned int hv[16];
#pragma unroll
        for (int i = 0; i < 16; ++i) sn[i] = ssrc[lo + i];
#pragma unroll
        for (int i = 0; i < 16; ++i) asv[i] = AS[sn[i]];
#pragma unroll
        for (int i = 0; i < 16; ++i)
            hv[i] = *(const unsigned int*)&Hb[(size_t)sn[i] * D + 2 * l];
#pragma unroll
        for (int i = 0; i < 16; ++i) {
            float v = asv[i] + adn;
            v = (v > 0.f) ? v : 0.2f * v;
            float w = __expf(v);
            s += w;
            float h0 = __uint_as_float(hv[i] << 16);
            float h1 = __uint_as_float(hv[i] & 0xffff0000u);
            acc.x = fmaf(w, h0, acc.x);
            acc.y = fmaf(w, h1, acc.y);
        }
        lo += 16;
    }
    if (lo < e1) {                            // masked final chunk, no serial tail
        int n = e1 - lo;
        int sn[16]; float asv[16]; unsigned int hv[16];
#pragma unroll
        for (int i = 0; i < 16; ++i) {
            int e = lo + ((i < n) ? i : (n - 1));
            sn[i] = ssrc[e];
        }
#pragma unroll
        for (int i = 0; i < 16; ++i) asv[i] = AS[sn[i]];
#pragma unroll
        for (int i = 0; i < 16; ++i)
            hv[i] = *(const unsigned int*)&Hb[(size_t)sn[i] * D + 2 * l];
#pragma unroll
        for (int i = 0; i < 16; ++i) {
            float v = asv[i] + adn;
            v = (v > 0.f) ? v : 0.2f * v;
            float w = (i < n) ? __expf(v) : 0.f;
            s += w;
            float h0 = __uint_as_float(hv[i] << 16);
            float h1 = __uint_as_float(hv[i] & 0xffff0000u);
            acc.x = fmaf(w, h0, acc.x);
            acc.y = fmaf(w, h1, acc.y);
        }
    }

    float inv = 1.f / (s + 1e-16f);
    float2 bv = ((const float2*)bias)[l];
    float o0 = acc.x * inv + bv.x;
    float o1 = acc.y * inv + bv.y;
    if (LAYER == 1) {
        float2 xs = *(const float2*)&Xskip[(size_t)node * D + 2 * l];
        o0 = fmaxf(0.1f * xs.x + 0.9f * o0, 0.f);
        o1 = fmaxf(0.1f * xs.y + 0.9f * o1, 0.f);
    }
    *(float2*)&OUT[(size_t)node * D + 2 * l] = make_float2(o0, o1);
}

// ---------------- launcher ----------------

extern "C" void kernel_launch(void* const* d_in, const int* in_sizes, int n_in,
                              void* d_out, int out_size, void* d_ws, size_t ws_size,
                              hipStream_t stream) {
    const float* x   = (const float*)d_in[0];
    const int*   adj = (const int*)d_in[1];   // int32 per harness contract
    // d_in[2] = edge_attr, ignored (edge_dim=None in reference)
    const float* W1  = (const float*)d_in[3];
    const float* as1 = (const float*)d_in[4];
    const float* ad1 = (const float*)d_in[5];
    const float* b1  = (const float*)d_in[6];
    const float* W2  = (const float*)d_in[7];
    const float* as2 = (const float*)d_in[8];
    const float* ad2 = (const float*)d_in[9];
    const float* b2  = (const float*)d_in[10];
    float* out = (float*)d_out;

    char* ws = (char*)d_ws;
    size_t off = 0;
    auto alloc = [&](size_t bytes) -> void* {
        void* p = ws + off;
        off = (off + bytes + 255) & ~(size_t)255;
        return p;
    };
    __hip_bfloat16* Hb = (__hip_bfloat16*)alloc((size_t)N_NODES * D * 2);  // 12.8 MB
    float* AS     = (float*)alloc((size_t)N_NODES * 4);
    float* AD     = (float*)alloc((size_t)N_NODES * 4);
    int*   deg    = (int*)alloc((size_t)N_NODES * 4);
    int*   rowptr = (int*)alloc((size_t)(N_NODES + 1) * 4);
    int*   cursor = (int*)alloc((size_t)N_NODES * 4);
    int*   ssrc   = (int*)alloc((size_t)N_EDGES * 4);         // 3.2 MB
    int*   parts  = (int*)alloc(256 * 4);
    float* T      = out;   // layer-1 output lives in d_out; dead before final write

    const int EB = (N_EDGES + 255) / 256;
    const int NB = (N_NODES + 255) / 256;   // 196

    hipMemsetAsync(deg, 0, (size_t)N_NODES * 4, stream);
    count_kernel<<<EB, 256, 0, stream>>>(adj, deg);
    scan1_kernel<<<NB, 256, 0, stream>>>(deg, rowptr, parts);
    scan2_kernel<<<1, 256, 0, stream>>>(parts, NB);
    scan3_kernel<<<NB, 256, 0, stream>>>(rowptr, parts, cursor);
    scatter_kernel<<<EB, 256, 0, stream>>>(adj, cursor, ssrc);

    const int GB = (N_NODES + 63) / 64;     // 782
    const int AB = (N_NODES + 3) / 4;       // 12500 (4 nodes/block, 1 wave each)

    // layer 1
    gemm_kernel<<<GB, 256, 0, stream>>>(x, W1, as1, ad1, Hb, AS, AD);
    agg_kernel<1><<<AB, 256, 0, stream>>>(Hb, AS, AD, rowptr, ssrc, b1, x, T);
    // layer 2
    gemm_kernel<<<GB, 256, 0, stream>>>(T, W2, as2, ad2, Hb, AS, AD);
    agg_kernel<2><<<AB, 256, 0, stream>>>(Hb, AS, AD, rowptr, ssrc, b2, nullptr, out);
}